// Round 8
// baseline (352.005 us; speedup 1.0000x reference)
//
#include <hip/hip_runtime.h>
#include <hip/hip_fp16.h>
#include <hip/hip_bf16.h>

// SplineConv MI355X (gfx950). fp32 in/out. R19:
//  - R18 CONFIRMED occupancy-quantum theory (VGPR 32, occupancy 81%) but
//    spilled: WRITE_SIZE 12.5->87.5MB = scratch (demand ~72 > 64 budget).
//  - R19 = R18 feature-split structure with registers that FIT:
//     * per-chunk record loads (16 live VGPRs, 8 VMEM/chunk/wave) replaced by
//       2-register 64-edge window + __shfl (ds_bpermute) pulls (R12 pattern);
//       ONE 8B coalesced load per wave per 64 edges.
//     * window sentinel-padded with half(+inf) => hat==0 exactly => ok-mask
//       compare chain deleted (~24 VALU/chunk).
//     * live set ~45 arch + 16 AGPR acc = ~61 <= 64 budget -> no spill,
//       32 waves/CU stands.
//  - everything else identical to R18: wave p owns feature slots c>>4 in
//    {2p,2p+1} (permuted gather = ONE dword/edge-row), acc[2][2]=16 AGPR,
//    launch_bounds(1024,8), 61.8KB LDS, epilogue/final/prep unchanged.
// Scatter-as-GEMM per node wave + root-folded MFMA epilogue (R9/R10-validated).

#define NN    50000
#define EE    1600000
#define NPB   16             // nodes per block (16 waves: 8 node-pairs x 2 feat-halves)
#define KD    1664           // 26*64: 25 conv slices + root slice
#define ASTB  1672           // accS row stride (bf16 elems)

#define NB    391            // coarse buckets = ceil(NN/128)
#define NSH   4              // shards per bucket
#define CCAP  1280           // per-shard capacity (lambda=1024, +8 sigma)
#define CSTR  16             // ccur stride in u32 (64B pad -> own cacheline)

// prep-kernel grid sections (edges first so they start immediately)
#define REC_B 6250           // EE/256 exactly
#define XB_B  1563           // ceil(NN*64/8/256)
#define WT_B  104            // 64*KD/4/256 exactly

typedef unsigned short ushort_t;
typedef __attribute__((ext_vector_type(8))) short short8;
typedef __attribute__((ext_vector_type(4))) float f32x4;

static __device__ __forceinline__ ushort_t f2bf(float f) {
  union { float f; unsigned u; } v; v.f = f;
  return (ushort_t)((v.u + 0x7fffu + ((v.u >> 16) & 1u)) >> 16);  // RNE
}
static __device__ __forceinline__ unsigned pk2bf(float a, float b) {
  __hip_bfloat162 h = __float22bfloat162_rn(make_float2(a, b));   // v_cvt_pk_bf16_f32
  union { __hip_bfloat162 h; unsigned u; } cv; cv.h = h; return cv.u;
}
union S8 { short8 s; unsigned u[4]; };

// ---------------- K: fused pass A. Sections: [0,REC_B) edges; [.., +XB_B) xb; rest wt.
__global__ __launch_bounds__(256) void k_prep(
    const int* __restrict__ ei, const float* __restrict__ pseudo,
    int* __restrict__ ccur, uint2* __restrict__ coarse,
    const float* __restrict__ x, ushort_t* __restrict__ xb,
    const float* __restrict__ w, const float* __restrict__ root,
    ushort_t* __restrict__ wt, int useXB) {
  const int b = blockIdx.x;
  const int tid = threadIdx.x;
  if (b < REC_B) {
    // ---- coarse scatter: record {col(u16) | row7(u8)<<16, fp16(v0)|fp16(v1)<<16}
    int e = b * 256 + tid;                    // EE == REC_B*256 exactly
    int row = ei[e], col = ei[EE + e];
    float2 pv = ((const float2*)pseudo)[e];
    float v0 = pv.x * 4.0f, v1 = pv.y * 4.0f;
    unsigned h0 = __half_as_ushort(__float2half(v0));
    unsigned h1 = __half_as_ushort(__float2half(v1));
    int c4 = (row >> 7) * NSH + (tid & (NSH - 1));
    int slot = atomicAdd(&ccur[c4 * CSTR], 1);
    if (slot < CCAP)                          // P(overflow) ~ 0 (8 sigma)
      coarse[(size_t)c4 * CCAP + slot] =
          make_uint2((unsigned)col | ((unsigned)(row & 127) << 16), h0 | (h1 << 16));
  } else if (b < REC_B + XB_B) {
    // ---- xb = bf16(x), 8 elems/thread (RNE identical to f2bf)
    if (!useXB) return;
    int t = (b - REC_B) * 256 + tid;
    if (t < NN * 8) {
      const float4* xp = (const float4*)x + (size_t)t * 2;
      float4 aa = xp[0], bb = xp[1];
      S8 o;
      o.u[0] = pk2bf(aa.x, aa.y); o.u[1] = pk2bf(aa.z, aa.w);
      o.u[2] = pk2bf(bb.x, bb.y); o.u[3] = pk2bf(bb.z, bb.w);
      ((short8*)xb)[t] = o.s;
    }
  } else {
    // ---- wt with PERMUTED K-slots: slot c of group kp holds input-feature
    // fi = 4*(c&15) + (c>>4)  (matches B-fragment dword gather + spill slots)
    int t = (b - REC_B - XB_B) * 256 + tid;
    int idx = t * 4;                          // KD%4==0 -> same o for all 4
    if (idx < 64 * KD) {
      int o = idx / KD, k = idx - o * KD;
#pragma unroll
      for (int q = 0; q < 4; ++q) {
        int kk = k + q;
        int kp = kk >> 6, c = kk & 63;
        int fi = 4 * (c & 15) + (c >> 4);
        wt[idx + q] = (kp < 25) ? f2bf(w[(kp * 64 + fi) * 64 + o])
                                : f2bf(root[fi * 64 + o]);
      }
    }
  }
}

// ---------------- K: pass B. 1 block per coarse bucket -> exact CSR + packed nfo.
__global__ __launch_bounds__(256) void k_sort(
    const int* __restrict__ ccur, const uint2* __restrict__ coarse,
    uint2* __restrict__ recs, uint2* __restrict__ nfo) {
  __shared__ int cnt[128], lpos[128], scn[128], red[256];
  const int c = blockIdx.x, tid = threadIdx.x;
  if (tid < 128) cnt[tid] = 0;
  // base = total edges in buckets < c (read 64B-padded counters, L2-hot)
  const int pc = c * NSH;
  int a = 0;
  for (int i = tid; i < pc; i += 256) a += min(ccur[i * CSTR], CCAP);
  red[tid] = a;
  __syncthreads();
  for (int s = 128; s > 0; s >>= 1) { if (tid < s) red[tid] += red[tid + s]; __syncthreads(); }
  const int base = red[0];
  // count phase (LDS atomics over 128 rows)
  for (int s = 0; s < NSH; ++s) {
    int n = min(ccur[(pc + s) * CSTR], CCAP);
    const uint2* seg = coarse + (size_t)(pc + s) * CCAP;
    for (int i = tid; i < n; i += 256) atomicAdd(&cnt[(seg[i].x >> 16) & 127], 1);
  }
  __syncthreads();
  // inclusive scan (Hillis-Steele, 128 lanes)
  if (tid < 128) scn[tid] = cnt[tid];
  __syncthreads();
  for (int ofs = 1; ofs < 128; ofs <<= 1) {
    int v = 0;
    if (tid < 128 && tid >= ofs) v = scn[tid - ofs];
    __syncthreads();
    if (tid < 128 && tid >= ofs) scn[tid] += v;
    __syncthreads();
  }
  if (tid < 128) {
    int excl = scn[tid] - cnt[tid];
    lpos[tid] = base + excl;
    int row = c * 128 + tid;
    if (row < NN) nfo[row] = make_uint2((unsigned)(base + excl), (unsigned)cnt[tid]);
  }
  __syncthreads();
  // scatter to exact CSR slots
  for (int s = 0; s < NSH; ++s) {
    int n = min(ccur[(pc + s) * CSTR], CCAP);
    const uint2* seg = coarse + (size_t)(pc + s) * CCAP;
    for (int i = tid; i < n; i += 256) {
      uint2 r = seg[i];
      int dst = atomicAdd(&lpos[(r.x >> 16) & 127], 1);
      recs[dst] = make_uint2(r.x & 0xFFFFu, r.y);
    }
  }
}

// ---------------- K: main fused. 1 block = 16 nodes; 16 waves = 8 node-pairs
// x 2 feature-halves; each wave serially does 2 nodes (half features each).
// Records via 2-reg 64-edge window + __shfl (sentinel half-inf => hat==0).
// acc[2][2]=16 AGPR + ~45 arch <= 64 (launch_bounds(1024,8)) -> 32 waves/CU.
template <bool XBF>
__global__ __launch_bounds__(1024, 8) void k_main(
    const uint2* __restrict__ recs, const uint2* __restrict__ nfo,
    const float* __restrict__ x, const ushort_t* __restrict__ xb,
    const ushort_t* __restrict__ wt, const float* __restrict__ bias,
    float* __restrict__ out) {
  __shared__ ushort_t accS[NPB * ASTB];   // 53.5 KB, bf16, MFMA-A layout
  __shared__ float    outp[2 * NPB * 64]; // 8 KB, per-kh partials (2 halves)
  __shared__ float    sinv[NPB];
  const int tid = threadIdx.x;
  const int lane = tid & 63;
  const int w = tid >> 6;                 // wave id in [0,16)
  const int p = w & 1;                    // feature half
  const int np = w >> 1;                  // node-pair in [0,8)
  const int nb = blockIdx.x * NPB;

  const int m15 = lane & 15, quad = lane >> 4;
  const float r0f = (float)(m15 / 5),        c0f = (float)(m15 % 5);
  const float r1f = (float)((16 + m15) / 5), c1f = (float)((16 + m15) % 5);

#pragma unroll
  for (int nd = 0; nd < 2; ++nd) {        // node-pair: nodes 2*np, 2*np+1
    const int row = (np << 1) + nd;
    const int node = nb + row;
    const uint2 nf = nfo[node];           // packed {start, deg}, one 8B load
    const int m = (int)nf.y;
    const float dcf = (float)max(m, 1);
    if (p == 0 && lane == 0) sinv[row] = 1.0f / dcf;
    // root slice (permuted slots, split): wave p writes slots c in [32p,32p+32)
    if (lane < 32) {
      int c = (p << 5) + lane;
      int fi = 4 * (c & 15) + (c >> 4);
      accS[row * ASTB + 1600 + c] = f2bf(x[(size_t)node * 64 + fi] * dcf);
    }

    f32x4 acc[2][2];                      // [mtile][ntile-half], 16 AGPRs
#pragma unroll
    for (int a = 0; a < 2; ++a)
#pragma unroll
      for (int b = 0; b < 2; ++b) acc[a][b] = (f32x4){0.f, 0.f, 0.f, 0.f};

    // ---- 64-edge register window, one record per lane, sentinel-padded.
    // sentinel: col=0 (valid addr), v=half(+inf) => hat = fmax(0,1-inf) = 0.
    const uint2* bket = recs + nf.x;
    unsigned rcx = 0u, rcy = 0x7C007C00u;
    if (lane < m) { uint2 rr = bket[lane]; rcx = rr.x; rcy = rr.y; }

    for (int e0 = 0; e0 < m; e0 += 32) {  // K=32 edge chunks
      if (e0 && !(e0 & 63)) {             // refill window (rare: deg > 64)
        rcx = 0u; rcy = 0x7C007C00u;
        int idx = e0 + lane;
        if (idx < m) { uint2 rr = bket[idx]; rcx = rr.x; rcy = rr.y; }
      }
      const int eb = (e0 & 32) + quad * 8;
      unsigned g[8], pj[8];
      float2 gf[8];
#pragma unroll
      for (int j = 0; j < 8; ++j) {       // shfl pull + immediate gather issue
        unsigned cjv = (unsigned)__shfl((int)rcx, eb + j);
        pj[j] = (unsigned)__shfl((int)rcy, eb + j);
        if (XBF)
          g[j] = *(const unsigned*)(xb + ((size_t)cjv << 6) + (m15 << 2) + (p << 1));
        else
          gf[j] = *(const float2*)(x + ((size_t)cjv << 6) + (m15 << 2) + (p << 1));
      }
      // ---- hats (VALU) overlap the gather latency; no mask (sentinel)
      S8 aT0, aT1, bT[2];
#pragma unroll
      for (int pp = 0; pp < 4; ++pp) {
        float a0[2], a1[2];
#pragma unroll
        for (int q = 0; q < 2; ++q) {
          unsigned pv = pj[2 * pp + q];
          float v0 = __half2float(__ushort_as_half((ushort_t)(pv & 0xFFFFu)));
          float v1 = __half2float(__ushort_as_half((ushort_t)(pv >> 16)));
          a0[q] = fmaxf(0.f, 1.f - fabsf(v0 - r0f)) * fmaxf(0.f, 1.f - fabsf(v1 - c0f));
          a1[q] = fmaxf(0.f, 1.f - fabsf(v0 - r1f)) * fmaxf(0.f, 1.f - fabsf(v1 - c1f));
        }
        aT0.u[pp] = pk2bf(a0[0], a0[1]);
        aT1.u[pp] = pk2bf(a1[0], a1[1]);
      }
      if (XBF) {
#pragma unroll
        for (int pp = 0; pp < 4; ++pp) {
          bT[0].u[pp] = (g[2 * pp] & 0xFFFFu) | (g[2 * pp + 1] << 16);
          bT[1].u[pp] = (g[2 * pp] >> 16)     | (g[2 * pp + 1] & 0xFFFF0000u);
        }
      } else {
#pragma unroll
        for (int pp = 0; pp < 4; ++pp) {
          bT[0].u[pp] = pk2bf(gf[2 * pp].x, gf[2 * pp + 1].x);
          bT[1].u[pp] = pk2bf(gf[2 * pp].y, gf[2 * pp + 1].y);
        }
      }
      __builtin_amdgcn_s_setprio(1);
#pragma unroll
      for (int t = 0; t < 2; ++t) {
        acc[0][t] = __builtin_amdgcn_mfma_f32_16x16x32_bf16(aT0.s, bT[t].s, acc[0][t], 0, 0, 0);
        acc[1][t] = __builtin_amdgcn_mfma_f32_16x16x32_bf16(aT1.s, bT[t].s, acc[1][t], 0, 0, 0);
      }
      __builtin_amdgcn_s_setprio(0);
    }

    // spill acc -> accS; kp = mt*16 + quad*4 + r, slot = (2p+t)*16 + m15
#pragma unroll
    for (int mt = 0; mt < 2; ++mt)
#pragma unroll
      for (int r = 0; r < 4; ++r) {
        int kp = mt * 16 + quad * 4 + r;
        if (kp < 25) {
#pragma unroll
          for (int t = 0; t < 2; ++t)
            accS[row * ASTB + kp * 64 + ((p << 1) + t) * 16 + m15] =
                f2bf(acc[mt][t][r]);
        }
      }
  }
  __syncthreads();

  if (w < 8) {  // MFMA epilogue: D[16 nodes][64] = accS[16][1664] @ wt^T
    // ntile = w&3 (output quarter), kh = w>>2 (K half, 26 kk each).
    // wt fragments prefetched depth-6 into statically-indexed regs.
    const int ntile = w & 3, kh = w >> 2;
    const int m2 = lane & 15, quad2 = lane >> 4;
    const int nn2 = ntile * 16 + m2;
    f32x4 d = {0.0f, 0.0f, 0.0f, 0.0f};
    const ushort_t* ab = &accS[m2 * ASTB + kh * 832 + quad2 * 8];
    const ushort_t* wb = &wt[(size_t)nn2 * KD + kh * 832 + quad2 * 8];
    short8 bfs[6];
#pragma unroll
    for (int kk = 0; kk < 6; ++kk) bfs[kk] = *(const short8*)(wb + kk * 32);
#pragma unroll
    for (int kk = 0; kk < 26; ++kk) {
      short8 af = *(const short8*)(ab + kk * 32);
      d = __builtin_amdgcn_mfma_f32_16x16x32_bf16(af, bfs[kk % 6], d, 0, 0, 0);
      if (kk + 6 < 26) bfs[kk % 6] = *(const short8*)(wb + (kk + 6) * 32);
    }
#pragma unroll
    for (int r = 0; r < 4; ++r)
      outp[kh * (NPB * 64) + (quad2 * 4 + r) * 64 + ntile * 16 + m2] = d[r];
  }
  __syncthreads();

  {  // final: out = (conv + x*dc@root) * (1/dc) + bias; 1024 threads x 1 elem
    int nl = tid >> 6, o = tid & 63;
    float conv = outp[tid] + outp[NPB * 64 + tid];
    out[(size_t)(nb + nl) * 64 + o] = conv * sinv[nl] + bias[o];
  }
}

// ---------------- sentinel: unambiguous "workspace too small" signature
__global__ void k_sentinel(float* __restrict__ out) {
  int i = blockIdx.x * 256 + threadIdx.x;
  if (i < NN * 64) out[i] = 1000.0f;
}

extern "C" void kernel_launch(void* const* d_in, const int* in_sizes, int n_in,
                              void* d_out, int out_size, void* d_ws, size_t ws_size,
                              hipStream_t stream) {
  const float* x      = (const float*)d_in[0];
  const int*   ei     = (const int*)d_in[1];
  const float* pseudo = (const float*)d_in[2];
  const float* w      = (const float*)d_in[3];
  const float* root   = (const float*)d_in[4];
  const float* bias   = (const float*)d_in[5];
  float* out = (float*)d_out;
  (void)in_sizes; (void)n_in; (void)out_size;

  char* ws = (char*)d_ws;
  size_t off = 0;
  auto alloc = [&](size_t bytes) { size_t r = off; off += (bytes + 511) & ~(size_t)511; return r; };
  ushort_t* wt     = (ushort_t*)(ws + alloc((size_t)64 * KD * 2));          // 213 KB
  int*      ccur   = (int*)(ws + alloc((size_t)NB * NSH * CSTR * 4));       // 100 KB
  uint2*    nfo    = (uint2*)(ws + alloc((size_t)NN * 8));                  // 400 KB
  uint2*    recs   = (uint2*)(ws + alloc((size_t)EE * 8));                  // 12.8 MB
  uint2*    coarse = (uint2*)(ws + alloc((size_t)NB * NSH * CCAP * 8));     // 16.0 MB
  size_t baseNeed  = off;
  ushort_t* xb     = (ushort_t*)(ws + alloc((size_t)NN * 64 * 2));          // 6.4 MB (optional)
  size_t fullNeed  = off;

  if (ws_size < baseNeed) {
    k_sentinel<<<(NN * 64 + 255) / 256, 256, 0, stream>>>(out);
    return;
  }
  const int useXB = (ws_size >= fullNeed) ? 1 : 0;

  hipMemsetAsync(ccur, 0, (size_t)NB * NSH * CSTR * 4, stream);
  k_prep<<<REC_B + XB_B + WT_B, 256, 0, stream>>>(ei, pseudo, ccur, coarse,
                                                  x, xb, w, root, wt, useXB);
  k_sort<<<NB, 256, 0, stream>>>(ccur, coarse, recs, nfo);
  if (useXB)
    k_main<true><<<NN / NPB, 1024, 0, stream>>>(recs, nfo, x, xb, wt, bias, out);
  else
    k_main<false><<<NN / NPB, 1024, 0, stream>>>(recs, nfo, x, xb, wt, bias, out);
}

// Round 9
// 303.289 us; speedup vs baseline: 1.1606x; 1.1606x over previous
//
#include <hip/hip_runtime.h>
#include <hip/hip_fp16.h>
#include <hip/hip_bf16.h>

// SplineConv MI355X (gfx950). fp32 in/out. R20:
//  - Occupancy ladder fully mapped (R11..R19): <=64 total regs -> 32 waves/CU
//    but forced 32/32 arch/acc split => catastrophic spill (R18/R19, WRITE
//    87->170MB); <=128 regs -> 16 waves/CU no spill (R17, 139us, only ~84/128
//    regs used). Granular allocation REFUTED by R11 (84 regs -> 16 not 20).
//  - R20 = R17 structure + the spare ~44 regs spent on explicit depth-2
//    latency hiding at 16 waves/CU:
//     * both nodes' nfo + root-x + 64-edge record WINDOWS load at wave start
//       (node B's window latency hides under node A's entire compute);
//     * per node, BOTH chunks' gathers issue back-to-back (16 dwordx2 in
//       flight) before compute -> compiler emits counted vmcnt(8); chunk-1
//       latency hides under chunk-0 hats+MFMA;
//     * straight-line if(m>32){ii,cc} branch keeps waitcnts path-local;
//     * sentinel windows (half +inf -> hat==0) delete main-path masks.
//  - deg>64 tail + fp32 path: R17 masked do_chunk (correctness-only).
//  - launch_bounds(512,4) = 128-reg budget; LDS 61.9KB -> 2 blocks/CU.
// Scatter-as-GEMM per node wave + root-folded MFMA epilogue (R9/R10-validated).

#define NN    50000
#define EE    1600000
#define NPB   16             // nodes per block (8 waves x 2 nodes)
#define KD    1664           // 26*64: 25 conv slices + root slice
#define ASTB  1672           // accS row stride (bf16 elems)

#define NB    391            // coarse buckets = ceil(NN/128)
#define NSH   4              // shards per bucket
#define CCAP  1280           // per-shard capacity (lambda=1024, +8 sigma)
#define CSTR  16             // ccur stride in u32 (64B pad -> own cacheline)

// prep-kernel grid sections (edges first so they start immediately)
#define REC_B 6250           // EE/256 exactly
#define XB_B  1563           // ceil(NN*64/8/256)
#define WT_B  104            // 64*KD/4/256 exactly

typedef unsigned short ushort_t;
typedef __attribute__((ext_vector_type(8))) short short8;
typedef __attribute__((ext_vector_type(4))) float f32x4;

static __device__ __forceinline__ ushort_t f2bf(float f) {
  union { float f; unsigned u; } v; v.f = f;
  return (ushort_t)((v.u + 0x7fffu + ((v.u >> 16) & 1u)) >> 16);  // RNE
}
static __device__ __forceinline__ unsigned pk2bf(float a, float b) {
  __hip_bfloat162 h = __float22bfloat162_rn(make_float2(a, b));   // v_cvt_pk_bf16_f32
  union { __hip_bfloat162 h; unsigned u; } cv; cv.h = h; return cv.u;
}
union S8 { short8 s; unsigned u[4]; };

// ---------------- K: fused pass A. Sections: [0,REC_B) edges; [.., +XB_B) xb; rest wt.
__global__ __launch_bounds__(256) void k_prep(
    const int* __restrict__ ei, const float* __restrict__ pseudo,
    int* __restrict__ ccur, uint2* __restrict__ coarse,
    const float* __restrict__ x, ushort_t* __restrict__ xb,
    const float* __restrict__ w, const float* __restrict__ root,
    ushort_t* __restrict__ wt, int useXB) {
  const int b = blockIdx.x;
  const int tid = threadIdx.x;
  if (b < REC_B) {
    // ---- coarse scatter: record {col(u16) | row7(u8)<<16, fp16(v0)|fp16(v1)<<16}
    int e = b * 256 + tid;                    // EE == REC_B*256 exactly
    int row = ei[e], col = ei[EE + e];
    float2 pv = ((const float2*)pseudo)[e];
    float v0 = pv.x * 4.0f, v1 = pv.y * 4.0f;
    unsigned h0 = __half_as_ushort(__float2half(v0));
    unsigned h1 = __half_as_ushort(__float2half(v1));
    int c4 = (row >> 7) * NSH + (tid & (NSH - 1));
    int slot = atomicAdd(&ccur[c4 * CSTR], 1);
    if (slot < CCAP)                          // P(overflow) ~ 0 (8 sigma)
      coarse[(size_t)c4 * CCAP + slot] =
          make_uint2((unsigned)col | ((unsigned)(row & 127) << 16), h0 | (h1 << 16));
  } else if (b < REC_B + XB_B) {
    // ---- xb = bf16(x), 8 elems/thread (RNE identical to f2bf)
    if (!useXB) return;
    int t = (b - REC_B) * 256 + tid;
    if (t < NN * 8) {
      const float4* xp = (const float4*)x + (size_t)t * 2;
      float4 aa = xp[0], bb = xp[1];
      S8 o;
      o.u[0] = pk2bf(aa.x, aa.y); o.u[1] = pk2bf(aa.z, aa.w);
      o.u[2] = pk2bf(bb.x, bb.y); o.u[3] = pk2bf(bb.z, bb.w);
      ((short8*)xb)[t] = o.s;
    }
  } else {
    // ---- wt with PERMUTED K-slots: slot c of group kp holds input-feature
    // fi = 4*(c&15) + (c>>4)  (matches B-fragment dwordx2 gather + spill slots)
    int t = (b - REC_B - XB_B) * 256 + tid;
    int idx = t * 4;                          // KD%4==0 -> same o for all 4
    if (idx < 64 * KD) {
      int o = idx / KD, k = idx - o * KD;
#pragma unroll
      for (int q = 0; q < 4; ++q) {
        int kk = k + q;
        int kp = kk >> 6, c = kk & 63;
        int fi = 4 * (c & 15) + (c >> 4);
        wt[idx + q] = (kp < 25) ? f2bf(w[(kp * 64 + fi) * 64 + o])
                                : f2bf(root[fi * 64 + o]);
      }
    }
  }
}

// ---------------- K: pass B. 1 block per coarse bucket -> exact CSR + packed nfo.
__global__ __launch_bounds__(256) void k_sort(
    const int* __restrict__ ccur, const uint2* __restrict__ coarse,
    uint2* __restrict__ recs, uint2* __restrict__ nfo) {
  __shared__ int cnt[128], lpos[128], scn[128], red[256];
  const int c = blockIdx.x, tid = threadIdx.x;
  if (tid < 128) cnt[tid] = 0;
  // base = total edges in buckets < c (read 64B-padded counters, L2-hot)
  const int pc = c * NSH;
  int a = 0;
  for (int i = tid; i < pc; i += 256) a += min(ccur[i * CSTR], CCAP);
  red[tid] = a;
  __syncthreads();
  for (int s = 128; s > 0; s >>= 1) { if (tid < s) red[tid] += red[tid + s]; __syncthreads(); }
  const int base = red[0];
  // count phase (LDS atomics over 128 rows)
  for (int s = 0; s < NSH; ++s) {
    int n = min(ccur[(pc + s) * CSTR], CCAP);
    const uint2* seg = coarse + (size_t)(pc + s) * CCAP;
    for (int i = tid; i < n; i += 256) atomicAdd(&cnt[(seg[i].x >> 16) & 127], 1);
  }
  __syncthreads();
  // inclusive scan (Hillis-Steele, 128 lanes)
  if (tid < 128) scn[tid] = cnt[tid];
  __syncthreads();
  for (int ofs = 1; ofs < 128; ofs <<= 1) {
    int v = 0;
    if (tid < 128 && tid >= ofs) v = scn[tid - ofs];
    __syncthreads();
    if (tid < 128 && tid >= ofs) scn[tid] += v;
    __syncthreads();
  }
  if (tid < 128) {
    int excl = scn[tid] - cnt[tid];
    lpos[tid] = base + excl;
    int row = c * 128 + tid;
    if (row < NN) nfo[row] = make_uint2((unsigned)(base + excl), (unsigned)cnt[tid]);
  }
  __syncthreads();
  // scatter to exact CSR slots
  for (int s = 0; s < NSH; ++s) {
    int n = min(ccur[(pc + s) * CSTR], CCAP);
    const uint2* seg = coarse + (size_t)(pc + s) * CCAP;
    for (int i = tid; i < n; i += 256) {
      uint2 r = seg[i];
      int dst = atomicAdd(&lpos[(r.x >> 16) & 127], 1);
      recs[dst] = make_uint2(r.x & 0xFFFFu, r.y);
    }
  }
}

// ---------------- shfl window records + issue 8 dwordx2 gathers for one chunk
static __device__ __forceinline__ void issue_chunk(
    unsigned wx, unsigned wy, int base, int quad, int m15,
    const ushort_t* __restrict__ xb, unsigned (&pj)[8], uint2 (&g)[8]) {
#pragma unroll
  for (int j = 0; j < 8; ++j) {
    int e = base + quad * 8 + j;
    unsigned cjv = (unsigned)__shfl((int)wx, e);
    pj[j] = (unsigned)__shfl((int)wy, e);
    g[j] = *(const uint2*)(xb + ((size_t)cjv << 6) + (m15 << 2));
  }
}

// ---------------- hats + pack + 8 MFMA for one staged chunk (no masks; windows
// are sentinel-padded with half(+inf) -> hat == 0 exactly)
static __device__ __forceinline__ void compute_chunk(
    const unsigned (&pj)[8], const uint2 (&g)[8],
    float r0f, float c0f, float r1f, float c1f, f32x4 (&acc)[2][4]) {
  S8 aT0, aT1, bT[4];
#pragma unroll
  for (int p = 0; p < 4; ++p) {
    float a0[2], a1[2];
#pragma unroll
    for (int q = 0; q < 2; ++q) {
      unsigned pv = pj[2 * p + q];
      float v0 = __half2float(__ushort_as_half((ushort_t)(pv & 0xFFFFu)));
      float v1 = __half2float(__ushort_as_half((ushort_t)(pv >> 16)));
      a0[q] = fmaxf(0.f, 1.f - fabsf(v0 - r0f)) * fmaxf(0.f, 1.f - fabsf(v1 - c0f));
      a1[q] = fmaxf(0.f, 1.f - fabsf(v0 - r1f)) * fmaxf(0.f, 1.f - fabsf(v1 - c1f));
    }
    aT0.u[p] = pk2bf(a0[0], a0[1]);
    aT1.u[p] = pk2bf(a1[0], a1[1]);
  }
#pragma unroll
  for (int p = 0; p < 4; ++p) {
    bT[0].u[p] = (g[2 * p].x & 0xFFFFu) | (g[2 * p + 1].x << 16);
    bT[1].u[p] = (g[2 * p].x >> 16)     | (g[2 * p + 1].x & 0xFFFF0000u);
    bT[2].u[p] = (g[2 * p].y & 0xFFFFu) | (g[2 * p + 1].y << 16);
    bT[3].u[p] = (g[2 * p].y >> 16)     | (g[2 * p + 1].y & 0xFFFF0000u);
  }
  __builtin_amdgcn_s_setprio(1);
#pragma unroll
  for (int t = 0; t < 4; ++t) {
    acc[0][t] = __builtin_amdgcn_mfma_f32_16x16x32_bf16(aT0.s, bT[t].s, acc[0][t], 0, 0, 0);
    acc[1][t] = __builtin_amdgcn_mfma_f32_16x16x32_bf16(aT1.s, bT[t].s, acc[1][t], 0, 0, 0);
  }
  __builtin_amdgcn_s_setprio(0);
}

// ---------------- masked direct-load chunk (deg>64 tail + fp32 fallback path)
template <bool XBF>
static __device__ __forceinline__ void do_chunk(
    const uint2 (&rq)[8], int kb, int m, int quad, int m15,
    float r0f, float c0f, float r1f, float c1f,
    const ushort_t* __restrict__ xb, const float* __restrict__ x,
    f32x4 (&acc)[2][4]) {
  unsigned cj[8], pj[8];
#pragma unroll
  for (int j = 0; j < 8; ++j) {
    cj[j] = min(rq[j].x, (unsigned)(NN - 1));
    pj[j] = rq[j].y;
  }
  uint2 g[8];
  float gf[4][8];
  if (XBF) {
#pragma unroll
    for (int j = 0; j < 8; ++j)
      g[j] = *(const uint2*)(xb + ((size_t)cj[j] << 6) + (m15 << 2));
  } else {
#pragma unroll
    for (int j = 0; j < 8; ++j) {
      float4 v = *(const float4*)(x + ((size_t)cj[j] << 6) + (m15 << 2));
      gf[0][j] = v.x; gf[1][j] = v.y; gf[2][j] = v.z; gf[3][j] = v.w;
    }
  }
  S8 aT0, aT1, bT[4];
#pragma unroll
  for (int p = 0; p < 4; ++p) {
    float a0[2], a1[2];
#pragma unroll
    for (int q = 0; q < 2; ++q) {
      int j = 2 * p + q;
      unsigned pv = pj[j];
      float v0 = __half2float(__ushort_as_half((ushort_t)(pv & 0xFFFFu)));
      float v1 = __half2float(__ushort_as_half((ushort_t)(pv >> 16)));
      bool ok = (kb + quad * 8 + j) < m;
      float p0 = fmaxf(0.f, 1.f - fabsf(v0 - r0f)) * fmaxf(0.f, 1.f - fabsf(v1 - c0f));
      float p1 = fmaxf(0.f, 1.f - fabsf(v0 - r1f)) * fmaxf(0.f, 1.f - fabsf(v1 - c1f));
      a0[q] = ok ? p0 : 0.0f;
      a1[q] = ok ? p1 : 0.0f;
    }
    aT0.u[p] = pk2bf(a0[0], a0[1]);
    aT1.u[p] = pk2bf(a1[0], a1[1]);
  }
  if (XBF) {
#pragma unroll
    for (int p = 0; p < 4; ++p) {
      bT[0].u[p] = (g[2 * p].x & 0xFFFFu) | (g[2 * p + 1].x << 16);
      bT[1].u[p] = (g[2 * p].x >> 16)     | (g[2 * p + 1].x & 0xFFFF0000u);
      bT[2].u[p] = (g[2 * p].y & 0xFFFFu) | (g[2 * p + 1].y << 16);
      bT[3].u[p] = (g[2 * p].y >> 16)     | (g[2 * p + 1].y & 0xFFFF0000u);
    }
  } else {
#pragma unroll
    for (int p = 0; p < 4; ++p)
#pragma unroll
      for (int t = 0; t < 4; ++t)
        bT[t].u[p] = pk2bf(gf[t][2 * p], gf[t][2 * p + 1]);
  }
#pragma unroll
  for (int t = 0; t < 4; ++t) {
    acc[0][t] = __builtin_amdgcn_mfma_f32_16x16x32_bf16(aT0.s, bT[t].s, acc[0][t], 0, 0, 0);
    acc[1][t] = __builtin_amdgcn_mfma_f32_16x16x32_bf16(aT1.s, bT[t].s, acc[1][t], 0, 0, 0);
  }
}

// ---------------- spill acc -> accS (kp = mt*16 + quad*4 + r, slot = nt*16+m15)
static __device__ __forceinline__ void spill_acc(
    ushort_t* accS, int row, int quad, int m15, const f32x4 (&acc)[2][4]) {
#pragma unroll
  for (int mt = 0; mt < 2; ++mt)
#pragma unroll
    for (int r = 0; r < 4; ++r) {
      int kp = mt * 16 + quad * 4 + r;
      if (kp < 25) {
#pragma unroll
        for (int nt = 0; nt < 4; ++nt)
          accS[row * ASTB + kp * 64 + nt * 16 + m15] = f2bf(acc[mt][nt][r]);
      }
    }
}

// ---------------- K: main fused. 1 block = 16 nodes, 8 waves x 2 nodes.
// launch_bounds(512,4) = 128-reg budget (proven no-spill region); 16 waves/CU.
template <bool XBF>
__global__ __launch_bounds__(512, 4) void k_main(
    const uint2* __restrict__ recs, const uint2* __restrict__ nfo,
    const float* __restrict__ x, const ushort_t* __restrict__ xb,
    const ushort_t* __restrict__ wt, const float* __restrict__ bias,
    float* __restrict__ out) {
  __shared__ ushort_t accS[NPB * ASTB];   // 53.5 KB, bf16, MFMA-A layout
  __shared__ float    outp[2 * NPB * 64]; // 8 KB, per-kh partials (2 halves)
  __shared__ float    sinv[NPB];
  const int tid = threadIdx.x;
  const int lane = tid & 63;
  const int w = tid >> 6;                 // wave id in [0,8)
  const int nb = blockIdx.x * NPB;

  const int m15 = lane & 15, quad = lane >> 4;
  const float r0f = (float)(m15 / 5),        c0f = (float)(m15 % 5);
  const float r1f = (float)((16 + m15) / 5), c1f = (float)((16 + m15) % 5);
  const int fl = 4 * m15 + quad;          // permuted feature for slot=lane

  const int rowA = w << 1, rowB = rowA + 1;
  const int nodeA = nb + rowA, nodeB = nb + rowB;

  // ---- wave-start burst: nfo x2, root-x x2, record windows x2 (all in flight
  // together; node B's latency hides under node A's compute)
  const uint2 nfA = nfo[nodeA], nfB = nfo[nodeB];
  const float rxA = x[(size_t)nodeA * 64 + fl];
  const float rxB = x[(size_t)nodeB * 64 + fl];
  const int mA = (int)nfA.y, mB = (int)nfB.y;
  unsigned wAx = 0u, wAy = 0x7C007C00u, wBx = 0u, wBy = 0x7C007C00u;
  if (lane < mA) { uint2 rr = recs[nfA.x + lane]; wAx = rr.x; wAy = rr.y; }
  if (lane < mB) { uint2 rr = recs[nfB.x + lane]; wBx = rr.x; wBy = rr.y; }

  const float dcfA = (float)max(mA, 1), dcfB = (float)max(mB, 1);
  if (lane == 0) { sinv[rowA] = 1.0f / dcfA; sinv[rowB] = 1.0f / dcfB; }
  // root slice (permuted slots): accS[row][1600+c] = bf16(x[node][perm(c)]*dc)
  accS[rowA * ASTB + 1600 + lane] = f2bf(rxA * dcfA);
  accS[rowB * ASTB + 1600 + lane] = f2bf(rxB * dcfB);

  f32x4 acc[2][4];
#pragma unroll
  for (int a = 0; a < 2; ++a)
#pragma unroll
    for (int b = 0; b < 4; ++b) acc[a][b] = (f32x4){0.f, 0.f, 0.f, 0.f};

  if (XBF) {
    // ---- node A: issue both chunks, then compute (counted vmcnt pipelines)
    if (mA > 32) {
      unsigned pj0[8], pj1[8]; uint2 g0[8], g1[8];
      issue_chunk(wAx, wAy, 0,  quad, m15, xb, pj0, g0);
      issue_chunk(wAx, wAy, 32, quad, m15, xb, pj1, g1);
      compute_chunk(pj0, g0, r0f, c0f, r1f, c1f, acc);
      compute_chunk(pj1, g1, r0f, c0f, r1f, c1f, acc);
    } else if (mA > 0) {
      unsigned pj0[8]; uint2 g0[8];
      issue_chunk(wAx, wAy, 0, quad, m15, xb, pj0, g0);
      compute_chunk(pj0, g0, r0f, c0f, r1f, c1f, acc);
    }
    for (int e0 = 64; e0 < mA; e0 += 32) {   // essentially never (deg<=64)
      uint2 rq[8];
#pragma unroll
      for (int j = 0; j < 8; ++j) rq[j] = recs[nfA.x + e0 + quad * 8 + j];
      do_chunk<true>(rq, e0, mA, quad, m15, r0f, c0f, r1f, c1f, xb, x, acc);
    }
    spill_acc(accS, rowA, quad, m15, acc);

    // ---- node B (window already resident since wave start)
#pragma unroll
    for (int a = 0; a < 2; ++a)
#pragma unroll
      for (int b = 0; b < 4; ++b) acc[a][b] = (f32x4){0.f, 0.f, 0.f, 0.f};
    if (mB > 32) {
      unsigned pj0[8], pj1[8]; uint2 g0[8], g1[8];
      issue_chunk(wBx, wBy, 0,  quad, m15, xb, pj0, g0);
      issue_chunk(wBx, wBy, 32, quad, m15, xb, pj1, g1);
      compute_chunk(pj0, g0, r0f, c0f, r1f, c1f, acc);
      compute_chunk(pj1, g1, r0f, c0f, r1f, c1f, acc);
    } else if (mB > 0) {
      unsigned pj0[8]; uint2 g0[8];
      issue_chunk(wBx, wBy, 0, quad, m15, xb, pj0, g0);
      compute_chunk(pj0, g0, r0f, c0f, r1f, c1f, acc);
    }
    for (int e0 = 64; e0 < mB; e0 += 32) {
      uint2 rq[8];
#pragma unroll
      for (int j = 0; j < 8; ++j) rq[j] = recs[nfB.x + e0 + quad * 8 + j];
      do_chunk<true>(rq, e0, mB, quad, m15, r0f, c0f, r1f, c1f, xb, x, acc);
    }
    spill_acc(accS, rowB, quad, m15, acc);
  } else {
    // ---- fp32 fallback: unpipelined R17 flow (correctness path)
    for (int e0 = 0; e0 < mA; e0 += 32) {
      uint2 rq[8];
#pragma unroll
      for (int j = 0; j < 8; ++j) rq[j] = recs[nfA.x + e0 + quad * 8 + j];
      do_chunk<false>(rq, e0, mA, quad, m15, r0f, c0f, r1f, c1f, xb, x, acc);
    }
    spill_acc(accS, rowA, quad, m15, acc);
#pragma unroll
    for (int a = 0; a < 2; ++a)
#pragma unroll
      for (int b = 0; b < 4; ++b) acc[a][b] = (f32x4){0.f, 0.f, 0.f, 0.f};
    for (int e0 = 0; e0 < mB; e0 += 32) {
      uint2 rq[8];
#pragma unroll
      for (int j = 0; j < 8; ++j) rq[j] = recs[nfB.x + e0 + quad * 8 + j];
      do_chunk<false>(rq, e0, mB, quad, m15, r0f, c0f, r1f, c1f, xb, x, acc);
    }
    spill_acc(accS, rowB, quad, m15, acc);
  }
  __syncthreads();

  {  // MFMA epilogue: D[16 nodes][64] = accS[16][1664] @ wt^T
    // 8 waves: ntile = w&3 (output quarter), kh = w>>2 (K half, 26 kk each).
    // wt fragments prefetched depth-6 into statically-indexed regs.
    const int ntile = w & 3, kh = w >> 2;
    const int m2 = lane & 15, quad2 = lane >> 4;
    const int nn2 = ntile * 16 + m2;
    f32x4 d = {0.0f, 0.0f, 0.0f, 0.0f};
    const ushort_t* ab = &accS[m2 * ASTB + kh * 832 + quad2 * 8];
    const ushort_t* wb = &wt[(size_t)nn2 * KD + kh * 832 + quad2 * 8];
    short8 bfs[6];
#pragma unroll
    for (int kk = 0; kk < 6; ++kk) bfs[kk] = *(const short8*)(wb + kk * 32);
#pragma unroll
    for (int kk = 0; kk < 26; ++kk) {
      short8 af = *(const short8*)(ab + kk * 32);
      d = __builtin_amdgcn_mfma_f32_16x16x32_bf16(af, bfs[kk % 6], d, 0, 0, 0);
      if (kk + 6 < 26) bfs[kk % 6] = *(const short8*)(wb + (kk + 6) * 32);
    }
#pragma unroll
    for (int r = 0; r < 4; ++r)
      outp[kh * (NPB * 64) + (quad2 * 4 + r) * 64 + ntile * 16 + m2] = d[r];
  }
  __syncthreads();

  {  // final: out = (conv + x*dc@root) * (1/dc) + bias; 512 threads x 2 elems
#pragma unroll
    for (int h = 0; h < 2; ++h) {
      int i = h * 512 + tid;
      int nl = i >> 6, o = i & 63;
      float conv = outp[i] + outp[NPB * 64 + i];
      out[(size_t)(nb + nl) * 64 + o] = conv * sinv[nl] + bias[o];
    }
  }
}

// ---------------- sentinel: unambiguous "workspace too small" signature
__global__ void k_sentinel(float* __restrict__ out) {
  int i = blockIdx.x * 256 + threadIdx.x;
  if (i < NN * 64) out[i] = 1000.0f;
}

extern "C" void kernel_launch(void* const* d_in, const int* in_sizes, int n_in,
                              void* d_out, int out_size, void* d_ws, size_t ws_size,
                              hipStream_t stream) {
  const float* x      = (const float*)d_in[0];
  const int*   ei     = (const int*)d_in[1];
  const float* pseudo = (const float*)d_in[2];
  const float* w      = (const float*)d_in[3];
  const float* root   = (const float*)d_in[4];
  const float* bias   = (const float*)d_in[5];
  float* out = (float*)d_out;
  (void)in_sizes; (void)n_in; (void)out_size;

  char* ws = (char*)d_ws;
  size_t off = 0;
  auto alloc = [&](size_t bytes) { size_t r = off; off += (bytes + 511) & ~(size_t)511; return r; };
  ushort_t* wt     = (ushort_t*)(ws + alloc((size_t)64 * KD * 2));          // 213 KB
  int*      ccur   = (int*)(ws + alloc((size_t)NB * NSH * CSTR * 4));       // 100 KB
  uint2*    nfo    = (uint2*)(ws + alloc((size_t)NN * 8));                  // 400 KB
  uint2*    recs   = (uint2*)(ws + alloc((size_t)EE * 8));                  // 12.8 MB
  uint2*    coarse = (uint2*)(ws + alloc((size_t)NB * NSH * CCAP * 8));     // 16.0 MB
  size_t baseNeed  = off;
  ushort_t* xb     = (ushort_t*)(ws + alloc((size_t)NN * 64 * 2));          // 6.4 MB (optional)
  size_t fullNeed  = off;

  if (ws_size < baseNeed) {
    k_sentinel<<<(NN * 64 + 255) / 256, 256, 0, stream>>>(out);
    return;
  }
  const int useXB = (ws_size >= fullNeed) ? 1 : 0;

  hipMemsetAsync(ccur, 0, (size_t)NB * NSH * CSTR * 4, stream);
  k_prep<<<REC_B + XB_B + WT_B, 256, 0, stream>>>(ei, pseudo, ccur, coarse,
                                                  x, xb, w, root, wt, useXB);
  k_sort<<<NB, 256, 0, stream>>>(ccur, coarse, recs, nfo);
  if (useXB)
    k_main<true><<<NN / NPB, 512, 0, stream>>>(recs, nfo, x, xb, wt, bias, out);
  else
    k_main<false><<<NN / NPB, 512, 0, stream>>>(recs, nfo, x, xb, wt, bias, out);
}